// Round 7
// baseline (465.398 us; speedup 1.0000x reference)
//
#include <hip/hip_runtime.h>
#include <hip/hip_bf16.h>
#include <stdint.h>

// ---------------- problem dims (fixed by setup_inputs) ----------------
#define S_TOK   2048   // tokens (B*S)
#define DMODEL  2048   // D
#define HEXP    512    // H per expert
#define NEXP    32     // E
#define HSH     1024   // shared hidden
#define NPAIR   (S_TOK * 4)   // 8192 (token,expert) pairs, top_k=4
#define MAXTILES 96           // sum ceil(cnt_e/128) <= 8192/128 + 32 = 96

// meta layout (ints)
#define META_NT  0
#define META_TE  1
#define META_TP0 (1 + MAXTILES)
#define META_TM  (1 + 2 * MAXTILES)
#define META_SIZE (1 + 3 * MAXTILES)

typedef short  s16x8 __attribute__((ext_vector_type(8)));
typedef __bf16 b16x8 __attribute__((ext_vector_type(8)));
typedef float  f32x4 __attribute__((ext_vector_type(4)));

__device__ __forceinline__ f32x4 mfma16x16x32(s16x8 a, s16x8 b, f32x4 c) {
    return __builtin_amdgcn_mfma_f32_16x16x32_bf16(
        __builtin_bit_cast(b16x8, a), __builtin_bit_cast(b16x8, b), c, 0, 0, 0);
}

__device__ __forceinline__ unsigned short f2bf(float f) {
    union { float f; unsigned int u; } v; v.f = f;
    unsigned int u = v.u;
    return (unsigned short)((u + 0x7FFFu + ((u >> 16) & 1u)) >> 16);  // RNE
}

__device__ __forceinline__ float bf2f(unsigned short b) {
    union { unsigned int u; float f; } v; v.u = ((unsigned int)b) << 16;
    return v.f;
}

// async global->LDS, 16B per lane. LDS dest is wave-uniform base + lane*16.
__device__ __forceinline__ void gload16(const unsigned short* g, unsigned short* l) {
    __builtin_amdgcn_global_load_lds(
        (const __attribute__((address_space(1))) void*)(uintptr_t)g,
        (__attribute__((address_space(3))) void*)(uintptr_t)l, 16, 0, 0);
}

// ---------------- router: logits, sigmoid, biased top-4, coef softmax ----------------
__global__ __launch_bounds__(256)
void router_kernel(const float* __restrict__ x, const float* __restrict__ gate_w,
                   const float* __restrict__ expert_bias,
                   const float* __restrict__ coef_w, const float* __restrict__ coef_b,
                   int* __restrict__ inds, float* __restrict__ scores,
                   float* __restrict__ coefo)
{
    const int t = blockIdx.x;
    const int tid = threadIdx.x;
    const int lane = tid & 63;
    const int wave = tid >> 6;
    const float* xr = x + (size_t)t * DMODEL;

    float xv[32];
#pragma unroll
    for (int j = 0; j < 32; ++j) xv[j] = xr[lane + 64 * j];

    __shared__ float s_logits[NEXP];
    __shared__ float s_coef[2];

    for (int i = 0; i < 8; ++i) {
        const int e = wave * 8 + i;
        const float* wr = gate_w + (size_t)e * DMODEL;
        float p = 0.f;
#pragma unroll
        for (int j = 0; j < 32; ++j) p += xv[j] * wr[lane + 64 * j];
#pragma unroll
        for (int o = 32; o > 0; o >>= 1) p += __shfl_xor(p, o);
        if (lane == 0) s_logits[e] = p;
    }
    if (wave == 0) {
        for (int c = 0; c < 2; ++c) {
            const float* wr = coef_w + (size_t)c * DMODEL;
            float p = 0.f;
#pragma unroll
            for (int j = 0; j < 32; ++j) p += xv[j] * wr[lane + 64 * j];
#pragma unroll
            for (int o = 32; o > 0; o >>= 1) p += __shfl_xor(p, o);
            if (lane == 0) s_coef[c] = p;
        }
    }
    __syncthreads();
    if (tid == 0) {
        float routing[NEXP], biased[NEXP];
        for (int e = 0; e < NEXP; ++e) {
            const float r = 1.f / (1.f + expf(-s_logits[e]));
            routing[e] = r;
            biased[e] = r + expert_bias[e];
        }
        int sel[4]; float sc[4]; float ssum = 0.f;
        for (int k = 0; k < 4; ++k) {
            int best = 0; float bv = -1e30f;
            for (int e = 0; e < NEXP; ++e)
                if (biased[e] > bv) { bv = biased[e]; best = e; }  // strict > = lax.top_k tie rule
            sel[k] = best; sc[k] = routing[best]; ssum += sc[k];
            biased[best] = -1e30f;
        }
        const float inv = 1.f / (ssum + 1e-20f);
        for (int k = 0; k < 4; ++k) {
            inds[t * 4 + k] = sel[k];
            scores[t * 4 + k] = sc[k] * inv;
        }
        const float l0 = s_coef[0] + coef_b[0];
        const float l1 = s_coef[1] + coef_b[1];
        const float m = fmaxf(l0, l1);
        const float e0 = expf(l0 - m), e1 = expf(l1 - m);
        coefo[t * 2 + 0] = e0 / (e0 + e1);
        coefo[t * 2 + 1] = e1 / (e0 + e1);
    }
}

// ---------------- x: f32 -> bf16 ----------------
__global__ __launch_bounds__(256)
void xcast_kernel(const float* __restrict__ x, unsigned short* __restrict__ xb)
{
    const int i = (blockIdx.x * 256 + threadIdx.x) * 4;
    const float4 v = *reinterpret_cast<const float4*>(x + i);
    ushort4 o;
    o.x = f2bf(v.x); o.y = f2bf(v.y); o.z = f2bf(v.z); o.w = f2bf(v.w);
    *reinterpret_cast<ushort4*>(xb + i) = o;
}

// ---------------- transpose-convert: f32 [K][N] -> bf16 [N][K] (per batch z) ------
__global__ __launch_bounds__(256)
void tconv_kernel(const float* __restrict__ src, unsigned short* __restrict__ dst,
                  const int K, const int N)
{
    __shared__ unsigned short T[64][80];   // [n][k], padded rows (160B)
    const size_t boff = (size_t)blockIdx.z * K * N;
    const float* s = src + boff;
    unsigned short* d = dst + boff;
    const int n0 = blockIdx.x * 64, k0 = blockIdx.y * 64;
    const int tid = threadIdx.x;

    const int n4 = (tid & 15) * 4;
    const int kr = tid >> 4;
#pragma unroll
    for (int i = 0; i < 4; ++i) {
        const int k = kr + i * 16;
        const float4 v = *reinterpret_cast<const float4*>(s + (size_t)(k0 + k) * N + n0 + n4);
        T[n4 + 0][k] = f2bf(v.x);
        T[n4 + 1][k] = f2bf(v.y);
        T[n4 + 2][k] = f2bf(v.z);
        T[n4 + 3][k] = f2bf(v.w);
    }
    __syncthreads();
    const int nw = tid >> 2;
    const int kc = (tid & 3) * 16;
    uint4* o = reinterpret_cast<uint4*>(d + (size_t)(n0 + nw) * K + k0 + kc);
    o[0] = *reinterpret_cast<const uint4*>(&T[nw][kc]);
    o[1] = *reinterpret_cast<const uint4*>(&T[nw][kc + 8]);
}

// ---------------- grouping: per-expert pair lists + tile table + token->pos map ----
__global__ __launch_bounds__(1024)
void group_kernel(const int* __restrict__ inds, const float* __restrict__ scores,
                  int* __restrict__ meta, int* __restrict__ pair_token,
                  float* __restrict__ pair_score, int* __restrict__ tok_pos)
{
    __shared__ int cnt[NEXP];
    __shared__ int off_s[NEXP];
    __shared__ int cur[NEXP];
    const int tid = threadIdx.x;
    if (tid < NEXP) cnt[tid] = 0;
    __syncthreads();
    for (int i = tid; i < NPAIR; i += 1024) atomicAdd(&cnt[inds[i]], 1);
    __syncthreads();
    if (tid == 0) {
        int run = 0, nt = 0;
        for (int e = 0; e < NEXP; ++e) {
            off_s[e] = run;
            const int c = cnt[e];
            for (int m0 = 0; m0 < c; m0 += 128) {
                meta[META_TE + nt] = e;
                meta[META_TP0 + nt] = run + m0;
                meta[META_TM + nt] = (c - m0 < 128) ? (c - m0) : 128;
                ++nt;
            }
            run += c;
        }
        meta[META_NT] = nt;
    }
    __syncthreads();
    if (tid < NEXP) cur[tid] = off_s[tid];
    __syncthreads();
    for (int i = tid; i < NPAIR; i += 1024) {
        const int e = inds[i];
        const int pos = atomicAdd(&cur[e], 1);
        pair_token[pos] = i >> 2;
        pair_score[pos] = scores[i];
        tok_pos[i] = pos;      // token t, slot k -> row in pair-major buffers
    }
}

// ---------------- gate+up GEMM (bf16 weights, pre-transposed), fused SwiGLU -------
// m97 structure: BM=128, BK=32, dual-B (g,u) 64 cols each; 4 waves 2x2 (wave tile
// 64m x 32n per mat). global_load_lds staging, double-buffered LDS, one barrier/K.
template <bool GATHER>
__global__ __launch_bounds__(256, 4)
void gateup_kernel(const unsigned short* __restrict__ xb,
                   const unsigned short* __restrict__ Bg_all,
                   const unsigned short* __restrict__ Bu_all,
                   unsigned short* __restrict__ act,
                   const int* __restrict__ meta, const int* __restrict__ pair_token,
                   const int NB)   // act/N stride: 512 (experts) or 1024 (shared)
{
    constexpr int NT = DMODEL / 32;   // 64 K-steps
    __shared__ unsigned short Al[2][128][32];
    __shared__ unsigned short Bgl[2][64][32];
    __shared__ unsigned short Bul[2][64][32];

    const int tid = threadIdx.x;
    const int lane = tid & 63;
    const int wave = tid >> 6;

    int p0, mval;
    const unsigned short *Bg, *Bu;
    if constexpr (GATHER) {
        const int tt = blockIdx.y;
        if (tt >= meta[META_NT]) return;
        const int e = meta[META_TE + tt];
        p0 = meta[META_TP0 + tt];
        mval = meta[META_TM + tt];
        const size_t eoff = (size_t)e * NB * DMODEL;
        Bg = Bg_all + eoff;
        Bu = Bu_all + eoff;
    } else {
        p0 = blockIdx.y * 128;
        mval = 128;
        Bg = Bg_all;
        Bu = Bu_all;
    }
    const int n0 = blockIdx.x * 64;

    const int sub  = lane >> 2;          // 0..15
    const int col8 = (lane & 3) * 8;     // k-offset in shorts
    const int arow0 = wave * 32 + sub;
    const int arow1 = arow0 + 16;
    int tok0, tok1;
    if constexpr (GATHER) {
        int q0 = p0 + arow0; if (q0 > NPAIR - 1) q0 = NPAIR - 1;
        int q1 = p0 + arow1; if (q1 > NPAIR - 1) q1 = NPAIR - 1;
        tok0 = pair_token[q0];
        tok1 = pair_token[q1];
    } else {
        tok0 = p0 + arow0;
        tok1 = p0 + arow1;
    }
    const unsigned short* asrc0 = xb + (size_t)tok0 * DMODEL + col8;
    const unsigned short* asrc1 = xb + (size_t)tok1 * DMODEL + col8;
    const int brow = wave * 16 + sub;
    const unsigned short* gsrc = Bg + (size_t)(n0 + brow) * DMODEL + col8;
    const unsigned short* usrc = Bu + (size_t)(n0 + brow) * DMODEL + col8;

    auto stage = [&](int buf, int k0) {
        gload16(asrc0 + k0, &Al[buf][wave * 32][0]);
        gload16(asrc1 + k0, &Al[buf][wave * 32 + 16][0]);
        gload16(gsrc + k0, &Bgl[buf][wave * 16][0]);
        gload16(usrc + k0, &Bul[buf][wave * 16][0]);
    };

    const int wm = wave >> 1, wn = wave & 1;
    const int fr = lane & 15, fq = lane >> 4;

    const f32x4 zero4 = {0.f, 0.f, 0.f, 0.f};
    f32x4 hacc[4][2], uacc[4][2];
#pragma unroll
    for (int m = 0; m < 4; ++m)
#pragma unroll
        for (int n = 0; n < 2; ++n) { hacc[m][n] = zero4; uacc[m][n] = zero4; }

    auto compute = [&](int buf) {
        const int ko = fq * 8;
        s16x8 af[4], bg[2], bu[2];
#pragma unroll
        for (int m = 0; m < 4; ++m)
            af[m] = *reinterpret_cast<const s16x8*>(&Al[buf][wm * 64 + m * 16 + fr][ko]);
#pragma unroll
        for (int n = 0; n < 2; ++n) {
            bg[n] = *reinterpret_cast<const s16x8*>(&Bgl[buf][wn * 32 + n * 16 + fr][ko]);
            bu[n] = *reinterpret_cast<const s16x8*>(&Bul[buf][wn * 32 + n * 16 + fr][ko]);
        }
#pragma unroll
        for (int m = 0; m < 4; ++m)
#pragma unroll
            for (int n = 0; n < 2; ++n) {
                hacc[m][n] = mfma16x16x32(af[m], bg[n], hacc[m][n]);
                uacc[m][n] = mfma16x16x32(af[m], bu[n], uacc[m][n]);
            }
    };

    stage(0, 0);
    __syncthreads();
#pragma unroll 1
    for (int t = 0; t < NT; ++t) {
        const int cur = t & 1;
        if (t + 1 < NT) stage(cur ^ 1, (t + 1) * 32);
        compute(cur);
        __syncthreads();
    }

    // epilogue: act = silu(h)*u -> bf16. C/D frag: col=lane&15, row=fq*4+r
#pragma unroll
    for (int m = 0; m < 4; ++m)
#pragma unroll
        for (int n = 0; n < 2; ++n) {
            const int col = n0 + wn * 32 + n * 16 + fr;
#pragma unroll
            for (int r = 0; r < 4; ++r) {
                const int rt = wm * 64 + m * 16 + fq * 4 + r;
                if (rt < mval) {
                    const float hv = hacc[m][n][r];
                    const float a = hv / (1.f + __expf(-hv)) * uacc[m][n][r];
                    act[(size_t)(p0 + rt) * NB + col] = f2bf(a);
                }
            }
        }
}

// ---------------- down GEMM: BM=128, BN=128, BK=32, bf16 transposed weights -------
// EXPERT=true : A = act rows (pair-major); epilogue writes y_pair bf16 (score applied).
// EXPERT=false: A = shared act; epilogue gathers token's 4 y_pair rows and writes
//               out = (sum y)*c0 + shared*c1  (no atomics anywhere).
template <bool EXPERT>
__global__ __launch_bounds__(256, 4)
void down_kernel(const unsigned short* __restrict__ act,
                 const unsigned short* __restrict__ Bd_all,
                 float* __restrict__ out, unsigned short* __restrict__ ypair,
                 const int* __restrict__ meta, const int* __restrict__ pair_token,
                 const float* __restrict__ pair_score, const float* __restrict__ coef,
                 const int* __restrict__ tok_pos,
                 const int KA)
{
    const int NT = KA / 32;   // 16 or 32
    __shared__ unsigned short Al[2][128][32];
    __shared__ unsigned short Bl[2][128][32];

    const int tid = threadIdx.x;
    const int lane = tid & 63;
    const int wave = tid >> 6;

    int p0, mval;
    const unsigned short* Bd;
    if constexpr (EXPERT) {
        const int tt = blockIdx.y;
        if (tt >= meta[META_NT]) return;
        const int e = meta[META_TE + tt];
        p0 = meta[META_TP0 + tt];
        mval = meta[META_TM + tt];
        Bd = Bd_all + (size_t)e * DMODEL * KA;
    } else {
        p0 = blockIdx.y * 128;
        mval = 128;
        Bd = Bd_all;
    }
    const int n0 = blockIdx.x * 128;

    const int sub  = lane >> 2;
    const int col8 = (lane & 3) * 8;
    int ar0 = p0 + wave * 32 + sub;
    int ar1 = ar0 + 16;
    if constexpr (EXPERT) {
        if (ar0 > NPAIR - 1) ar0 = NPAIR - 1;
        if (ar1 > NPAIR - 1) ar1 = NPAIR - 1;
    }
    const unsigned short* asrc0 = act + (size_t)ar0 * KA + col8;
    const unsigned short* asrc1 = act + (size_t)ar1 * KA + col8;
    const int brow = wave * 32 + sub;
    const unsigned short* bsrc0 = Bd + (size_t)(n0 + brow) * KA + col8;
    const unsigned short* bsrc1 = Bd + (size_t)(n0 + brow + 16) * KA + col8;

    auto stage = [&](int buf, int k0) {
        gload16(asrc0 + k0, &Al[buf][wave * 32][0]);
        gload16(asrc1 + k0, &Al[buf][wave * 32 + 16][0]);
        gload16(bsrc0 + k0, &Bl[buf][wave * 32][0]);
        gload16(bsrc1 + k0, &Bl[buf][wave * 32 + 16][0]);
    };

    const int wm = wave >> 1, wn = wave & 1;
    const int fr = lane & 15, fq = lane >> 4;

    const f32x4 zero4 = {0.f, 0.f, 0.f, 0.f};
    f32x4 acc[4][4];
#pragma unroll
    for (int m = 0; m < 4; ++m)
#pragma unroll
        for (int n = 0; n < 4; ++n) acc[m][n] = zero4;

    auto compute = [&](int buf) {
        const int ko = fq * 8;
        s16x8 af[4], bf[4];
#pragma unroll
        for (int m = 0; m < 4; ++m)
            af[m] = *reinterpret_cast<const s16x8*>(&Al[buf][wm * 64 + m * 16 + fr][ko]);
#pragma unroll
        for (int n = 0; n < 4; ++n)
            bf[n] = *reinterpret_cast<const s16x8*>(&Bl[buf][wn * 64 + n * 16 + fr][ko]);
#pragma unroll
        for (int m = 0; m < 4; ++m)
#pragma unroll
            for (int n = 0; n < 4; ++n)
                acc[m][n] = mfma16x16x32(af[m], bf[n], acc[m][n]);
    };

    stage(0, 0);
    __syncthreads();
#pragma unroll 1
    for (int t = 0; t < NT; ++t) {
        const int cur = t & 1;
        if (t + 1 < NT) stage(cur ^ 1, (t + 1) * 32);
        compute(cur);
        __syncthreads();
    }

#pragma unroll
    for (int m = 0; m < 4; ++m)
#pragma unroll
        for (int n = 0; n < 4; ++n) {
            const int col = n0 + wn * 64 + n * 16 + fr;
#pragma unroll
            for (int r = 0; r < 4; ++r) {
                const int rt = wm * 64 + m * 16 + fq * 4 + r;
                if (rt < mval) {
                    if constexpr (EXPERT) {
                        const int p = p0 + rt;
                        const float s = pair_score[p];
                        ypair[(size_t)p * DMODEL + col] = f2bf(acc[m][n][r] * s);
                    } else {
                        const int row = p0 + rt;     // token
                        float y4 = 0.f;
#pragma unroll
                        for (int k = 0; k < 4; ++k) {
                            const int pos = tok_pos[row * 4 + k];
                            y4 += bf2f(ypair[(size_t)pos * DMODEL + col]);
                        }
                        const float c0 = coef[row * 2 + 0];
                        const float c1 = coef[row * 2 + 1];
                        out[(size_t)row * DMODEL + col] = y4 * c0 + acc[m][n][r] * c1;
                    }
                }
            }
        }
}

// ---------------- launch ----------------
extern "C" void kernel_launch(void* const* d_in, const int* in_sizes, int n_in,
                              void* d_out, int out_size, void* d_ws, size_t ws_size,
                              hipStream_t stream)
{
    const float* x           = (const float*)d_in[0];
    const float* gate_w      = (const float*)d_in[1];
    const float* expert_bias = (const float*)d_in[2];
    const float* wg          = (const float*)d_in[3];
    const float* wu          = (const float*)d_in[4];
    const float* wd          = (const float*)d_in[5];
    const float* sg          = (const float*)d_in[6];
    const float* su          = (const float*)d_in[7];
    const float* sd          = (const float*)d_in[8];
    const float* coef_w      = (const float*)d_in[9];
    const float* coef_b      = (const float*)d_in[10];
    float* out = (float*)d_out;

    char* ws = (char*)d_ws;
    size_t off = 0;
    auto take = [&](size_t bytes) {
        char* p = ws + off;
        off = (off + bytes + 255) & ~(size_t)255;
        return p;
    };
    int*   inds     = (int*)  take((size_t)S_TOK * 4 * sizeof(int));
    float* scores   = (float*)take((size_t)S_TOK * 4 * sizeof(float));
    float* coefp    = (float*)take((size_t)S_TOK * 2 * sizeof(float));
    int*   meta     = (int*)  take((size_t)META_SIZE * sizeof(int));
    int*   pair_tok = (int*)  take((size_t)NPAIR * sizeof(int));
    float* pair_sc  = (float*)take((size_t)NPAIR * sizeof(float));
    int*   tok_pos  = (int*)  take((size_t)NPAIR * sizeof(int));
    unsigned short* xb    = (unsigned short*)take((size_t)S_TOK * DMODEL * 2);
    unsigned short* act   = (unsigned short*)take((size_t)NPAIR * HEXP * 2);
    unsigned short* shact = (unsigned short*)take((size_t)S_TOK * HSH * 2);
    unsigned short* ypair = (unsigned short*)take((size_t)NPAIR * DMODEL * 2);  // 33.5MB
    unsigned short* sgb   = (unsigned short*)take((size_t)HSH * DMODEL * 2);    // [HS][D]
    unsigned short* sub_  = (unsigned short*)take((size_t)HSH * DMODEL * 2);    // [HS][D]
    unsigned short* sdb   = (unsigned short*)take((size_t)DMODEL * HSH * 2);    // [D][HS]
    unsigned short* W1    = (unsigned short*)take((size_t)NEXP * DMODEL * HEXP * 2); // 64MB
    unsigned short* W2    = (unsigned short*)take((size_t)NEXP * DMODEL * HEXP * 2); // 64MB
    (void)ws_size; (void)in_sizes; (void)n_in; (void)out_size;

    router_kernel<<<S_TOK, 256, 0, stream>>>(x, gate_w, expert_bias, coef_w, coef_b,
                                             inds, scores, coefp);
    xcast_kernel<<<(S_TOK * DMODEL / 4) / 256, 256, 0, stream>>>(x, xb);
    group_kernel<<<1, 1024, 0, stream>>>(inds, scores, meta, pair_tok, pair_sc, tok_pos);

    // transpose-convert weights: f32 [K][N] -> bf16 [N][K]
    tconv_kernel<<<dim3(HSH / 64, DMODEL / 64, 1), 256, 0, stream>>>(sg, sgb, DMODEL, HSH);
    tconv_kernel<<<dim3(HSH / 64, DMODEL / 64, 1), 256, 0, stream>>>(su, sub_, DMODEL, HSH);
    tconv_kernel<<<dim3(DMODEL / 64, HSH / 64, 1), 256, 0, stream>>>(sd, sdb, HSH, DMODEL);
    tconv_kernel<<<dim3(HEXP / 64, DMODEL / 64, NEXP), 256, 0, stream>>>(wg, W1, DMODEL, HEXP);
    tconv_kernel<<<dim3(HEXP / 64, DMODEL / 64, NEXP), 256, 0, stream>>>(wu, W2, DMODEL, HEXP);

    // expert gate+up (+SwiGLU)
    gateup_kernel<true><<<dim3(HEXP / 64, MAXTILES), 256, 0, stream>>>(
        xb, W1, W2, act, meta, pair_tok, HEXP);
    // shared gate+up: N=1024, M=2048
    gateup_kernel<false><<<dim3(HSH / 64, S_TOK / 128), 256, 0, stream>>>(
        xb, sgb, sub_, shact, nullptr, nullptr, HSH);

    // wd -> bf16 [E][D][H] into W1 (wgb dead after expert gateup)
    tconv_kernel<<<dim3(DMODEL / 64, HEXP / 64, NEXP), 256, 0, stream>>>(wd, W1, HEXP, DMODEL);

    // expert down: y_pair[p][D] = (act_p . wd_e) * score_p   (plain bf16 stores)
    down_kernel<true><<<dim3(DMODEL / 128, MAXTILES), 256, 0, stream>>>(
        act, W1, out, ypair, meta, pair_tok, pair_sc, nullptr, tok_pos, HEXP);
    // shared down + gather 4 y_pair rows + coef mix -> out (each element written once)
    down_kernel<false><<<dim3(DMODEL / 128, S_TOK / 128), 256, 0, stream>>>(
        shact, sdb, out, ypair, nullptr, nullptr, nullptr, coefp, tok_pos, HSH);
}

// Round 8
// 432.094 us; speedup vs baseline: 1.0771x; 1.0771x over previous
//
#include <hip/hip_runtime.h>
#include <hip/hip_bf16.h>
#include <stdint.h>

// ---------------- problem dims (fixed by setup_inputs) ----------------
#define S_TOK   2048   // tokens (B*S)
#define DMODEL  2048   // D
#define HEXP    512    // H per expert
#define NEXP    32     // E
#define HSH     1024   // shared hidden
#define NPAIR   (S_TOK * 4)   // 8192 (token,expert) pairs, top_k=4
#define MAXTILES 96           // sum ceil(cnt_e/128) <= 8192/128 + 32 = 96

// meta layout (ints)
#define META_NT  0
#define META_TE  1
#define META_TP0 (1 + MAXTILES)
#define META_TM  (1 + 2 * MAXTILES)
#define META_SIZE (1 + 3 * MAXTILES)

typedef short  s16x8 __attribute__((ext_vector_type(8)));
typedef __bf16 b16x8 __attribute__((ext_vector_type(8)));
typedef float  f32x4 __attribute__((ext_vector_type(4)));

__device__ __forceinline__ f32x4 mfma16x16x32(s16x8 a, s16x8 b, f32x4 c) {
    return __builtin_amdgcn_mfma_f32_16x16x32_bf16(
        __builtin_bit_cast(b16x8, a), __builtin_bit_cast(b16x8, b), c, 0, 0, 0);
}

__device__ __forceinline__ unsigned short f2bf(float f) {
    union { float f; unsigned int u; } v; v.f = f;
    unsigned int u = v.u;
    return (unsigned short)((u + 0x7FFFu + ((u >> 16) & 1u)) >> 16);  // RNE
}

__device__ __forceinline__ float bf2f(unsigned short b) {
    union { unsigned int u; float f; } v; v.u = ((unsigned int)b) << 16;
    return v.f;
}

// async global->LDS, 16B per lane. LDS dest is wave-uniform base + lane*16.
__device__ __forceinline__ void gload16(const unsigned short* g, unsigned short* l) {
    __builtin_amdgcn_global_load_lds(
        (const __attribute__((address_space(1))) void*)(uintptr_t)g,
        (__attribute__((address_space(3))) void*)(uintptr_t)l, 16, 0, 0);
}

// counted waits (T4): never drain vmcnt to 0 in the steady-state loop
#define WAITV4() asm volatile("s_waitcnt vmcnt(4)" ::: "memory")
#define WAITV0() asm volatile("s_waitcnt vmcnt(0)" ::: "memory")

// ---------------- router: logits, sigmoid, biased top-4, coef softmax ----------------
__global__ __launch_bounds__(256)
void router_kernel(const float* __restrict__ x, const float* __restrict__ gate_w,
                   const float* __restrict__ expert_bias,
                   const float* __restrict__ coef_w, const float* __restrict__ coef_b,
                   int* __restrict__ inds, float* __restrict__ scores,
                   float* __restrict__ coefo)
{
    const int t = blockIdx.x;
    const int tid = threadIdx.x;
    const int lane = tid & 63;
    const int wave = tid >> 6;
    const float* xr = x + (size_t)t * DMODEL;

    float xv[32];
#pragma unroll
    for (int j = 0; j < 32; ++j) xv[j] = xr[lane + 64 * j];

    __shared__ float s_logits[NEXP];
    __shared__ float s_coef[2];

    for (int i = 0; i < 8; ++i) {
        const int e = wave * 8 + i;
        const float* wr = gate_w + (size_t)e * DMODEL;
        float p = 0.f;
#pragma unroll
        for (int j = 0; j < 32; ++j) p += xv[j] * wr[lane + 64 * j];
#pragma unroll
        for (int o = 32; o > 0; o >>= 1) p += __shfl_xor(p, o);
        if (lane == 0) s_logits[e] = p;
    }
    if (wave == 0) {
        for (int c = 0; c < 2; ++c) {
            const float* wr = coef_w + (size_t)c * DMODEL;
            float p = 0.f;
#pragma unroll
            for (int j = 0; j < 32; ++j) p += xv[j] * wr[lane + 64 * j];
#pragma unroll
            for (int o = 32; o > 0; o >>= 1) p += __shfl_xor(p, o);
            if (lane == 0) s_coef[c] = p;
        }
    }
    __syncthreads();
    if (tid == 0) {
        float routing[NEXP], biased[NEXP];
        for (int e = 0; e < NEXP; ++e) {
            const float r = 1.f / (1.f + expf(-s_logits[e]));
            routing[e] = r;
            biased[e] = r + expert_bias[e];
        }
        int sel[4]; float sc[4]; float ssum = 0.f;
        for (int k = 0; k < 4; ++k) {
            int best = 0; float bv = -1e30f;
            for (int e = 0; e < NEXP; ++e)
                if (biased[e] > bv) { bv = biased[e]; best = e; }  // strict > = lax.top_k tie rule
            sel[k] = best; sc[k] = routing[best]; ssum += sc[k];
            biased[best] = -1e30f;
        }
        const float inv = 1.f / (ssum + 1e-20f);
        for (int k = 0; k < 4; ++k) {
            inds[t * 4 + k] = sel[k];
            scores[t * 4 + k] = sc[k] * inv;
        }
        const float l0 = s_coef[0] + coef_b[0];
        const float l1 = s_coef[1] + coef_b[1];
        const float m = fmaxf(l0, l1);
        const float e0 = expf(l0 - m), e1 = expf(l1 - m);
        coefo[t * 2 + 0] = e0 / (e0 + e1);
        coefo[t * 2 + 1] = e1 / (e0 + e1);
    }
}

// ---------------- x: f32 -> bf16 ----------------
__global__ __launch_bounds__(256)
void xcast_kernel(const float* __restrict__ x, unsigned short* __restrict__ xb)
{
    const int i = (blockIdx.x * 256 + threadIdx.x) * 4;
    const float4 v = *reinterpret_cast<const float4*>(x + i);
    ushort4 o;
    o.x = f2bf(v.x); o.y = f2bf(v.y); o.z = f2bf(v.z); o.w = f2bf(v.w);
    *reinterpret_cast<ushort4*>(xb + i) = o;
}

// ---------------- transpose-convert: f32 [K][N] -> bf16 [N][K] (per batch z) ------
__global__ __launch_bounds__(256)
void tconv_kernel(const float* __restrict__ src, unsigned short* __restrict__ dst,
                  const int K, const int N)
{
    __shared__ unsigned short T[64][80];   // [n][k], padded rows (160B)
    const size_t boff = (size_t)blockIdx.z * K * N;
    const float* s = src + boff;
    unsigned short* d = dst + boff;
    const int n0 = blockIdx.x * 64, k0 = blockIdx.y * 64;
    const int tid = threadIdx.x;

    const int n4 = (tid & 15) * 4;
    const int kr = tid >> 4;
#pragma unroll
    for (int i = 0; i < 4; ++i) {
        const int k = kr + i * 16;
        const float4 v = *reinterpret_cast<const float4*>(s + (size_t)(k0 + k) * N + n0 + n4);
        T[n4 + 0][k] = f2bf(v.x);
        T[n4 + 1][k] = f2bf(v.y);
        T[n4 + 2][k] = f2bf(v.z);
        T[n4 + 3][k] = f2bf(v.w);
    }
    __syncthreads();
    const int nw = tid >> 2;
    const int kc = (tid & 3) * 16;
    uint4* o = reinterpret_cast<uint4*>(d + (size_t)(n0 + nw) * K + k0 + kc);
    o[0] = *reinterpret_cast<const uint4*>(&T[nw][kc]);
    o[1] = *reinterpret_cast<const uint4*>(&T[nw][kc + 8]);
}

// ---------------- grouping: per-expert pair lists + tile table + token->pos map ----
__global__ __launch_bounds__(1024)
void group_kernel(const int* __restrict__ inds, const float* __restrict__ scores,
                  int* __restrict__ meta, int* __restrict__ pair_token,
                  float* __restrict__ pair_score, int* __restrict__ tok_pos)
{
    __shared__ int cnt[NEXP];
    __shared__ int off_s[NEXP];
    __shared__ int cur[NEXP];
    const int tid = threadIdx.x;
    if (tid < NEXP) cnt[tid] = 0;
    __syncthreads();
    for (int i = tid; i < NPAIR; i += 1024) atomicAdd(&cnt[inds[i]], 1);
    __syncthreads();
    if (tid == 0) {
        int run = 0, nt = 0;
        for (int e = 0; e < NEXP; ++e) {
            off_s[e] = run;
            const int c = cnt[e];
            for (int m0 = 0; m0 < c; m0 += 128) {
                meta[META_TE + nt] = e;
                meta[META_TP0 + nt] = run + m0;
                meta[META_TM + nt] = (c - m0 < 128) ? (c - m0) : 128;
                ++nt;
            }
            run += c;
        }
        meta[META_NT] = nt;
    }
    __syncthreads();
    if (tid < NEXP) cur[tid] = off_s[tid];
    __syncthreads();
    for (int i = tid; i < NPAIR; i += 1024) {
        const int e = inds[i];
        const int pos = atomicAdd(&cur[e], 1);
        pair_token[pos] = i >> 2;
        pair_score[pos] = scores[i];
        tok_pos[i] = pos;      // token t, slot k -> row in pair-major buffers
    }
}

// ---------------- gate+up GEMM (bf16 weights, pre-transposed), fused SwiGLU -------
// BM=128, BK=32, dual-B (g,u) 64 cols each; 4 waves 2x2 (wave tile 64m x 32n per mat).
// 3-deep LDS pipeline with counted vmcnt(4) + raw s_barrier (T4): two tiles always in
// flight, each gets a full iteration of latency coverage. LDS XOR-swizzle via
// pre-swizzled global source (key (row&3)<<4 bytes): 8-way -> 4-way read conflicts.
template <bool GATHER>
__global__ __launch_bounds__(256, 3)
void gateup_kernel(const unsigned short* __restrict__ xb,
                   const unsigned short* __restrict__ Bg_all,
                   const unsigned short* __restrict__ Bu_all,
                   unsigned short* __restrict__ act,
                   const int* __restrict__ meta, const int* __restrict__ pair_token,
                   const int NB)   // act/N stride: 512 (experts) or 1024 (shared)
{
    constexpr int NT = DMODEL / 32;   // 64 K-steps
    __shared__ unsigned short Al[3][128][32];
    __shared__ unsigned short Bgl[3][64][32];
    __shared__ unsigned short Bul[3][64][32];

    const int tid = threadIdx.x;
    const int lane = tid & 63;
    const int wave = tid >> 6;

    int p0, mval;
    const unsigned short *Bg, *Bu;
    if constexpr (GATHER) {
        const int tt = blockIdx.y;
        if (tt >= meta[META_NT]) return;
        const int e = meta[META_TE + tt];
        p0 = meta[META_TP0 + tt];
        mval = meta[META_TM + tt];
        const size_t eoff = (size_t)e * NB * DMODEL;
        Bg = Bg_all + eoff;
        Bu = Bu_all + eoff;
    } else {
        p0 = blockIdx.y * 128;
        mval = 128;
        Bg = Bg_all;
        Bu = Bu_all;
    }
    const int n0 = blockIdx.x * 64;

    // staging geometry: lane -> (row sub = lane>>2, 16B chunk (lane&3)*8 shorts).
    // Pre-swizzle the SOURCE column by key = (sub&3)*8 so linear LDS writes produce
    // the swizzled layout the reader expects.
    const int sub  = lane >> 2;               // 0..15
    const int swz  = (sub & 3) * 8;           // XOR key in shorts
    const int col8 = ((lane & 3) * 8) ^ swz;  // swizzled k-offset within 32-short chunk
    const int arow0 = wave * 32 + sub;
    const int arow1 = arow0 + 16;
    int tok0, tok1;
    if constexpr (GATHER) {
        int q0 = p0 + arow0; if (q0 > NPAIR - 1) q0 = NPAIR - 1;
        int q1 = p0 + arow1; if (q1 > NPAIR - 1) q1 = NPAIR - 1;
        tok0 = pair_token[q0];
        tok1 = pair_token[q1];
    } else {
        tok0 = p0 + arow0;
        tok1 = p0 + arow1;
    }
    const unsigned short* asrc0 = xb + (size_t)tok0 * DMODEL + col8;
    const unsigned short* asrc1 = xb + (size_t)tok1 * DMODEL + col8;
    const int brow = wave * 16 + sub;
    const unsigned short* gsrc = Bg + (size_t)(n0 + brow) * DMODEL + col8;
    const unsigned short* usrc = Bu + (size_t)(n0 + brow) * DMODEL + col8;

    auto stage = [&](int buf, int k0) {
        gload16(asrc0 + k0, &Al[buf][wave * 32][0]);
        gload16(asrc1 + k0, &Al[buf][wave * 32 + 16][0]);
        gload16(gsrc + k0, &Bgl[buf][wave * 16][0]);
        gload16(usrc + k0, &Bul[buf][wave * 16][0]);
    };

    const int wm = wave >> 1, wn = wave & 1;
    const int fr = lane & 15, fq = lane >> 4;
    const int ko = (fq * 8) ^ ((fr & 3) * 8);   // swizzled fragment read offset

    const f32x4 zero4 = {0.f, 0.f, 0.f, 0.f};
    f32x4 hacc[4][2], uacc[4][2];
#pragma unroll
    for (int m = 0; m < 4; ++m)
#pragma unroll
        for (int n = 0; n < 2; ++n) { hacc[m][n] = zero4; uacc[m][n] = zero4; }

    auto compute = [&](int buf) {
        s16x8 af[4], bg[2], bu[2];
#pragma unroll
        for (int m = 0; m < 4; ++m)
            af[m] = *reinterpret_cast<const s16x8*>(&Al[buf][wm * 64 + m * 16 + fr][ko]);
#pragma unroll
        for (int n = 0; n < 2; ++n) {
            bg[n] = *reinterpret_cast<const s16x8*>(&Bgl[buf][wn * 32 + n * 16 + fr][ko]);
            bu[n] = *reinterpret_cast<const s16x8*>(&Bul[buf][wn * 32 + n * 16 + fr][ko]);
        }
#pragma unroll
        for (int m = 0; m < 4; ++m)
#pragma unroll
            for (int n = 0; n < 2; ++n) {
                hacc[m][n] = mfma16x16x32(af[m], bg[n], hacc[m][n]);
                uacc[m][n] = mfma16x16x32(af[m], bu[n], uacc[m][n]);
            }
    };

    // prologue: tiles 0,1 in flight; wait tile 0 only (vmcnt(4))
    stage(0, 0);
    stage(1, 32);
    WAITV4();
    __builtin_amdgcn_s_barrier();
    int b0 = 0, b1 = 1, b2 = 2;
#pragma unroll 1
    for (int t = 0; t < NT; ++t) {
        if (t + 2 < NT) stage(b2, (t + 2) * 32);   // keep 2 tiles in flight
        compute(b0);
        if (t + 2 < NT)      { WAITV4(); }         // tile t+1 ready; t+2 still flying
        else if (t + 1 < NT) { WAITV0(); }         // drain tail
        __builtin_amdgcn_s_barrier();
        const int tb = b0; b0 = b1; b1 = b2; b2 = tb;
    }

    // epilogue: act = silu(h)*u -> bf16. C/D frag: col=lane&15, row=fq*4+r
#pragma unroll
    for (int m = 0; m < 4; ++m)
#pragma unroll
        for (int n = 0; n < 2; ++n) {
            const int col = n0 + wn * 32 + n * 16 + fr;
#pragma unroll
            for (int r = 0; r < 4; ++r) {
                const int rt = wm * 64 + m * 16 + fq * 4 + r;
                if (rt < mval) {
                    const float hv = hacc[m][n][r];
                    const float a = hv / (1.f + __expf(-hv)) * uacc[m][n][r];
                    act[(size_t)(p0 + rt) * NB + col] = f2bf(a);
                }
            }
        }
}

// ---------------- down GEMM: BM=128, BN=128, BK=32, bf16 transposed weights -------
// Same 3-deep counted-vmcnt pipeline + swizzle.
// EXPERT=true : A = act rows (pair-major); epilogue writes y_pair bf16 (score applied).
// EXPERT=false: A = shared act; epilogue gathers token's 4 y_pair rows:
//               out = (sum y)*c0 + shared*c1  (no atomics anywhere).
template <bool EXPERT, int KA>
__global__ __launch_bounds__(256, 3)
void down_kernel(const unsigned short* __restrict__ act,
                 const unsigned short* __restrict__ Bd_all,
                 float* __restrict__ out, unsigned short* __restrict__ ypair,
                 const int* __restrict__ meta, const int* __restrict__ pair_token,
                 const float* __restrict__ pair_score, const float* __restrict__ coef,
                 const int* __restrict__ tok_pos)
{
    constexpr int NT = KA / 32;   // 16 or 32
    __shared__ unsigned short Al[3][128][32];
    __shared__ unsigned short Bl[3][128][32];

    const int tid = threadIdx.x;
    const int lane = tid & 63;
    const int wave = tid >> 6;

    int p0, mval;
    const unsigned short* Bd;
    if constexpr (EXPERT) {
        const int tt = blockIdx.y;
        if (tt >= meta[META_NT]) return;
        const int e = meta[META_TE + tt];
        p0 = meta[META_TP0 + tt];
        mval = meta[META_TM + tt];
        Bd = Bd_all + (size_t)e * DMODEL * KA;
    } else {
        p0 = blockIdx.y * 128;
        mval = 128;
        Bd = Bd_all;
    }
    const int n0 = blockIdx.x * 128;

    const int sub  = lane >> 2;
    const int swz  = (sub & 3) * 8;
    const int col8 = ((lane & 3) * 8) ^ swz;
    int ar0 = p0 + wave * 32 + sub;
    int ar1 = ar0 + 16;
    if constexpr (EXPERT) {
        if (ar0 > NPAIR - 1) ar0 = NPAIR - 1;
        if (ar1 > NPAIR - 1) ar1 = NPAIR - 1;
    }
    const unsigned short* asrc0 = act + (size_t)ar0 * KA + col8;
    const unsigned short* asrc1 = act + (size_t)ar1 * KA + col8;
    const int brow = wave * 32 + sub;
    const unsigned short* bsrc0 = Bd + (size_t)(n0 + brow) * KA + col8;
    const unsigned short* bsrc1 = Bd + (size_t)(n0 + brow + 16) * KA + col8;

    auto stage = [&](int buf, int k0) {
        gload16(asrc0 + k0, &Al[buf][wave * 32][0]);
        gload16(asrc1 + k0, &Al[buf][wave * 32 + 16][0]);
        gload16(bsrc0 + k0, &Bl[buf][wave * 32][0]);
        gload16(bsrc1 + k0, &Bl[buf][wave * 32 + 16][0]);
    };

    const int wm = wave >> 1, wn = wave & 1;
    const int fr = lane & 15, fq = lane >> 4;
    const int ko = (fq * 8) ^ ((fr & 3) * 8);

    const f32x4 zero4 = {0.f, 0.f, 0.f, 0.f};
    f32x4 acc[4][4];
#pragma unroll
    for (int m = 0; m < 4; ++m)
#pragma unroll
        for (int n = 0; n < 4; ++n) acc[m][n] = zero4;

    auto compute = [&](int buf) {
        s16x8 af[4], bf[4];
#pragma unroll
        for (int m = 0; m < 4; ++m)
            af[m] = *reinterpret_cast<const s16x8*>(&Al[buf][wm * 64 + m * 16 + fr][ko]);
#pragma unroll
        for (int n = 0; n < 4; ++n)
            bf[n] = *reinterpret_cast<const s16x8*>(&Bl[buf][wn * 64 + n * 16 + fr][ko]);
#pragma unroll
        for (int m = 0; m < 4; ++m)
#pragma unroll
            for (int n = 0; n < 4; ++n)
                acc[m][n] = mfma16x16x32(af[m], bf[n], acc[m][n]);
    };

    stage(0, 0);
    stage(1, 32);
    WAITV4();
    __builtin_amdgcn_s_barrier();
    int b0 = 0, b1 = 1, b2 = 2;
#pragma unroll 1
    for (int t = 0; t < NT; ++t) {
        if (t + 2 < NT) stage(b2, (t + 2) * 32);
        compute(b0);
        if (t + 2 < NT)      { WAITV4(); }
        else if (t + 1 < NT) { WAITV0(); }
        __builtin_amdgcn_s_barrier();
        const int tb = b0; b0 = b1; b1 = b2; b2 = tb;
    }

#pragma unroll
    for (int m = 0; m < 4; ++m)
#pragma unroll
        for (int n = 0; n < 4; ++n) {
            const int col = n0 + wn * 64 + n * 16 + fr;
#pragma unroll
            for (int r = 0; r < 4; ++r) {
                const int rt = wm * 64 + m * 16 + fq * 4 + r;
                if (rt < mval) {
                    if constexpr (EXPERT) {
                        const int p = p0 + rt;
                        const float s = pair_score[p];
                        ypair[(size_t)p * DMODEL + col] = f2bf(acc[m][n][r] * s);
                    } else {
                        const int row = p0 + rt;     // token
                        float y4 = 0.f;
#pragma unroll
                        for (int k = 0; k < 4; ++k) {
                            const int pos = tok_pos[row * 4 + k];
                            y4 += bf2f(ypair[(size_t)pos * DMODEL + col]);
                        }
                        const float c0 = coef[row * 2 + 0];
                        const float c1 = coef[row * 2 + 1];
                        out[(size_t)row * DMODEL + col] = y4 * c0 + acc[m][n][r] * c1;
                    }
                }
            }
        }
}

// ---------------- launch ----------------
extern "C" void kernel_launch(void* const* d_in, const int* in_sizes, int n_in,
                              void* d_out, int out_size, void* d_ws, size_t ws_size,
                              hipStream_t stream)
{
    const float* x           = (const float*)d_in[0];
    const float* gate_w      = (const float*)d_in[1];
    const float* expert_bias = (const float*)d_in[2];
    const float* wg          = (const float*)d_in[3];
    const float* wu          = (const float*)d_in[4];
    const float* wd          = (const float*)d_in[5];
    const float* sg          = (const float*)d_in[6];
    const float* su          = (const float*)d_in[7];
    const float* sd          = (const float*)d_in[8];
    const float* coef_w      = (const float*)d_in[9];
    const float* coef_b      = (const float*)d_in[10];
    float* out = (float*)d_out;

    char* ws = (char*)d_ws;
    size_t off = 0;
    auto take = [&](size_t bytes) {
        char* p = ws + off;
        off = (off + bytes + 255) & ~(size_t)255;
        return p;
    };
    int*   inds     = (int*)  take((size_t)S_TOK * 4 * sizeof(int));
    float* scores   = (float*)take((size_t)S_TOK * 4 * sizeof(float));
    float* coefp    = (float*)take((size_t)S_TOK * 2 * sizeof(float));
    int*   meta     = (int*)  take((size_t)META_SIZE * sizeof(int));
    int*   pair_tok = (int*)  take((size_t)NPAIR * sizeof(int));
    float* pair_sc  = (float*)take((size_t)NPAIR * sizeof(float));
    int*   tok_pos  = (int*)  take((size_t)NPAIR * sizeof(int));
    unsigned short* xb    = (unsigned short*)take((size_t)S_TOK * DMODEL * 2);
    unsigned short* act   = (unsigned short*)take((size_t)NPAIR * HEXP * 2);
    unsigned short* shact = (unsigned short*)take((size_t)S_TOK * HSH * 2);
    unsigned short* ypair = (unsigned short*)take((size_t)NPAIR * DMODEL * 2);  // 33.5MB
    unsigned short* sgb   = (unsigned short*)take((size_t)HSH * DMODEL * 2);    // [HS][D]
    unsigned short* sub_  = (unsigned short*)take((size_t)HSH * DMODEL * 2);    // [HS][D]
    unsigned short* sdb   = (unsigned short*)take((size_t)DMODEL * HSH * 2);    // [D][HS]
    unsigned short* W1    = (unsigned short*)take((size_t)NEXP * DMODEL * HEXP * 2); // 64MB
    unsigned short* W2    = (unsigned short*)take((size_t)NEXP * DMODEL * HEXP * 2); // 64MB
    (void)ws_size; (void)in_sizes; (void)n_in; (void)out_size;

    router_kernel<<<S_TOK, 256, 0, stream>>>(x, gate_w, expert_bias, coef_w, coef_b,
                                             inds, scores, coefp);
    xcast_kernel<<<(S_TOK * DMODEL / 4) / 256, 256, 0, stream>>>(x, xb);
    group_kernel<<<1, 1024, 0, stream>>>(inds, scores, meta, pair_tok, pair_sc, tok_pos);

    // transpose-convert weights: f32 [K][N] -> bf16 [N][K]
    tconv_kernel<<<dim3(HSH / 64, DMODEL / 64, 1), 256, 0, stream>>>(sg, sgb, DMODEL, HSH);
    tconv_kernel<<<dim3(HSH / 64, DMODEL / 64, 1), 256, 0, stream>>>(su, sub_, DMODEL, HSH);
    tconv_kernel<<<dim3(DMODEL / 64, HSH / 64, 1), 256, 0, stream>>>(sd, sdb, HSH, DMODEL);
    tconv_kernel<<<dim3(HEXP / 64, DMODEL / 64, NEXP), 256, 0, stream>>>(wg, W1, DMODEL, HEXP);
    tconv_kernel<<<dim3(HEXP / 64, DMODEL / 64, NEXP), 256, 0, stream>>>(wu, W2, DMODEL, HEXP);

    // expert gate+up (+SwiGLU)
    gateup_kernel<true><<<dim3(HEXP / 64, MAXTILES), 256, 0, stream>>>(
        xb, W1, W2, act, meta, pair_tok, HEXP);
    // shared gate+up: N=1024, M=2048
    gateup_kernel<false><<<dim3(HSH / 64, S_TOK / 128), 256, 0, stream>>>(
        xb, sgb, sub_, shact, nullptr, nullptr, HSH);

    // wd -> bf16 [E][D][H] into W1 (wgb dead after expert gateup)
    tconv_kernel<<<dim3(DMODEL / 64, HEXP / 64, NEXP), 256, 0, stream>>>(wd, W1, HEXP, DMODEL);

    // expert down: y_pair[p][D] = (act_p . wd_e) * score_p   (plain bf16 stores)
    down_kernel<true, HEXP><<<dim3(DMODEL / 128, MAXTILES), 256, 0, stream>>>(
        act, W1, out, ypair, meta, pair_tok, pair_sc, nullptr, tok_pos);
    // shared down + gather 4 y_pair rows + coef mix -> out (each element written once)
    down_kernel<false, HSH><<<dim3(DMODEL / 128, S_TOK / 128), 256, 0, stream>>>(
        shact, sdb, out, ypair, nullptr, nullptr, nullptr, coefp, tok_pos);
}